// Round 5
// baseline (686.048 us; speedup 1.0000x reference)
//
#include <hip/hip_runtime.h>
#include <hip/hip_bf16.h>
#include <cstdint>
#include <cstddef>

typedef __bf16 bf16x2 __attribute__((ext_vector_type(2)));
typedef __bf16 bf16x8 __attribute__((ext_vector_type(8)));
typedef float f32x4 __attribute__((ext_vector_type(4)));

__device__ __forceinline__ void gl_lds16(const __bf16* g, __bf16* l) {
    __builtin_amdgcn_global_load_lds(
        (const __attribute__((address_space(1))) unsigned int*)g,
        (__attribute__((address_space(3))) unsigned int*)l, 16, 0, 0);
}

// raw (unconverted) A registers: defer f32->bf16 cvt to the consume site so the
// vmcnt wait for the loads is a counted wait one full K-step after issue.
template <typename AT> struct ARaw;
template <> struct ARaw<float>  { float4 u, v; };
template <> struct ARaw<__bf16> { bf16x8 w; };

template <typename AT>
__device__ __forceinline__ void loadAraw(const AT* p, ARaw<AT>& r) {
    if constexpr (sizeof(AT) == 4) {
        r.u = *(const float4*)p;
        r.v = *(const float4*)(p + 4);
    } else {
        r.w = *(const bf16x8*)p;
    }
}

template <typename AT>
__device__ __forceinline__ bf16x8 cvtA(const ARaw<AT>& r) {
    if constexpr (sizeof(AT) == 4) {
        return (bf16x8){(__bf16)r.u.x, (__bf16)r.u.y, (__bf16)r.u.z, (__bf16)r.u.w,
                        (__bf16)r.v.x, (__bf16)r.v.y, (__bf16)r.v.z, (__bf16)r.v.w};
    } else {
        return r.w;
    }
}

// ---------------------------------------------------------------- U-set marking
__global__ __launch_bounds__(256) void mark_idx_kernel(const int* __restrict__ idx,
                                                       int* __restrict__ flagIdx,
                                                       int* __restrict__ flagU, int B) {
    int t = blockIdx.x * 256 + threadIdx.x;
    if (t < B) {
        int n = idx[t];
        flagIdx[n] = 1;
        flagU[n] = 1;
    }
}

// histogram of dst + mark sources of idx-edges (one pass over edges)
__global__ __launch_bounds__(256) void hist_mark_kernel(const int* __restrict__ esrc,
                                                        const int* __restrict__ edst,
                                                        const int* __restrict__ flagIdx,
                                                        int* __restrict__ deg,
                                                        int* __restrict__ flagU, int E) {
    int e = blockIdx.x * 256 + threadIdx.x;
    if (e < E) {
        int d = edst[e];
        atomicAdd(&deg[d], 1);
        if (flagIdx[d]) flagU[esrc[e]] = 1;
    }
}

// ---------------------------------------------------------------- scan (1 block, 8/thread) + U-compaction tail
__global__ __launch_bounds__(1024) void scan8_kernel(const int* __restrict__ deg,
                                                     int* __restrict__ off, int n,
                                                     const int* __restrict__ flagU,
                                                     int* __restrict__ U,
                                                     int* __restrict__ nU) {
    __shared__ int wsum[16];
    int tid = threadIdx.x, lane = tid & 63, wid = tid >> 6;
    if (tid == 0) off[0] = 0;
    int carry = 0;
    int nchunk = (n + 8191) >> 13;
    for (int c = 0; c < nchunk; ++c) {
        int base = (c << 13) + tid * 8;
        int4 a = *(const int4*)(deg + base);
        int4 b = *(const int4*)(deg + base + 4);
        int s[8];
        s[0] = a.x; s[1] = s[0] + a.y; s[2] = s[1] + a.z; s[3] = s[2] + a.w;
        s[4] = s[3] + b.x; s[5] = s[4] + b.y; s[6] = s[5] + b.z; s[7] = s[6] + b.w;
        int x = s[7];
        for (int o = 1; o < 64; o <<= 1) {
            int t = __shfl_up(x, o, 64);
            if (lane >= o) x += t;
        }
        if (lane == 63) wsum[wid] = x;
        __syncthreads();
        if (wid == 0 && lane < 16) {
            int w = wsum[lane];
            for (int o = 1; o < 16; o <<= 1) {
                int t = __shfl_up(w, o, 64);
                if (lane >= o) w += t;
            }
            wsum[lane] = w;
        }
        __syncthreads();
        int pre = carry + (wid ? wsum[wid - 1] : 0) + (x - s[7]);
#pragma unroll
        for (int i = 0; i < 8; ++i)
            if (base + i < n) off[base + i + 1] = pre + s[i];
        carry += wsum[15];
        __syncthreads();
    }
    // fused U-compaction (independent of the scan, needs only flagU)
    for (int i = tid; i < n; i += 1024)
        if (flagU[i]) U[atomicAdd(nU, 1)] = i;
}

__global__ __launch_bounds__(256) void scatter_kernel(const int* __restrict__ src,
                                                      const int* __restrict__ dst,
                                                      const int* __restrict__ off,
                                                      int* __restrict__ cursor,
                                                      int* __restrict__ srcs, int E) {
    int e = blockIdx.x * 256 + threadIdx.x;
    if (e < E) {
        int d = dst[e];
        int p = off[d] + atomicAdd(&cursor[d], 1);
        srcs[p] = src[e];
    }
}

// ---------------------------------------------------------------- weight prep
// w0t: [512,1024] bf16 rows ordered k,v,q,s ; w1t: [512,128] ; b0,b1: [512] f32 same order
__global__ __launch_bounds__(256) void pack_w_kernel(const float* __restrict__ wq0, const float* __restrict__ wk0,
                                                     const float* __restrict__ wv0, const float* __restrict__ ws0,
                                                     const float* __restrict__ wq1, const float* __restrict__ wk1,
                                                     const float* __restrict__ wv1, const float* __restrict__ ws1,
                                                     const float* __restrict__ bq0, const float* __restrict__ bk0,
                                                     const float* __restrict__ bv0, const float* __restrict__ bs0,
                                                     const float* __restrict__ bq1, const float* __restrict__ bk1,
                                                     const float* __restrict__ bv1, const float* __restrict__ bs1,
                                                     __bf16* __restrict__ w0t, __bf16* __restrict__ w1t,
                                                     float* __restrict__ b0, float* __restrict__ b1) {
    int i = blockIdx.x * 256 + threadIdx.x;
    const int S0 = 512 * 1024, S1 = 512 * 128;
    if (i < S0) {
        int n = i >> 10, k = i & 1023;
        int sel = n >> 7, c = n & 127;
        const float* w = (sel == 0) ? wk0 : (sel == 1) ? wv0 : (sel == 2) ? wq0 : ws0;
        w0t[i] = (__bf16)w[(size_t)k * 128 + c];
    } else if (i < S0 + S1) {
        int j = i - S0;
        int n = j >> 7, k = j & 127;
        int sel = n >> 7, c = n & 127;
        const float* w = (sel == 0) ? wk1 : (sel == 1) ? wv1 : (sel == 2) ? wq1 : ws1;
        w1t[j] = (__bf16)w[(size_t)k * 128 + c];
    } else if (i < S0 + S1 + 512) {
        int t = i - S0 - S1;
        int sel = t >> 7, c = t & 127;
        const float* b = (sel == 0) ? bk0 : (sel == 1) ? bv0 : (sel == 2) ? bq0 : bs0;
        b0[t] = b[c];
    } else if (i < S0 + S1 + 1024) {
        int t = i - S0 - S1 - 512;
        int sel = t >> 7, c = t & 127;
        const float* b = (sel == 0) ? bk1 : (sel == 1) ? bv1 : (sel == 2) ? bq1 : bs1;
        b1[t] = b[c];
    }
}

// ---------------------------------------------------------------- dual-sector MFMA GEMM
// R9 (= R8 resubmit, hardened): A-operand direct global->register (no LDS round-trip).
// Each wave's A rows are wave-private; the 4x reuse across wn-waves is served by L2.
// Per K-step: MFMA(k) from B-LDS + A-regs; cvt A(k+1) (compiler counted vmcnt);
// issue A(k+2) regs + B(k+2) gl_lds; then vmcnt(10|6) + s_barrier (B(k+1) resident;
// this step's 10|6 prefetch ops stay in flight -> no drain-to-0 anywhere in the loop).
// Uniform clamped tail: prefetches always issued (dead buffer slots / dead regs)
// so the vmcnt literals are exact every step.
// blockIdx.x <  s0blocks -> sector 0: Bt rows [0,256)   -> outb (bf16), rows rl0/n0
// blockIdx.x >= s0blocks -> sector 1: Bt rows [256,512) -> outf (f32),  rows rl1/n1
// Block tile 128(M) x 256(N), BK=32. 512 threads = 8 waves (2m x 4n), wave tile 64x64.
// B: triple-buffered LDS (48 KB), XOR-swizzled chunk layout (neutral-measured, kept).
template <typename AT>
__global__ __launch_bounds__(512, 2) void gemm_dual_kernel(const AT* __restrict__ A,
                                                           const __bf16* __restrict__ Bt,
                                                           const float* __restrict__ bias,
                                                           __bf16* __restrict__ outb,
                                                           float* __restrict__ outf,
                                                           const int* __restrict__ rl0,
                                                           const int* __restrict__ np0, int ns0,
                                                           const int* __restrict__ rl1,
                                                           const int* __restrict__ np1, int ns1,
                                                           int K, int s0blocks) {
    __shared__ __align__(16) __bf16 Bsl[3][256 * 32];   // 48 KB
    const int bx = blockIdx.x;
    const int sector = (bx >= s0blocks) ? 1 : 0;
    const int tile0  = sector ? bx - s0blocks : bx;
    const int tstr   = sector ? (gridDim.x - s0blocks) : s0blocks;
    const int* rowlist = sector ? rl1 : rl0;
    const int* nptr = sector ? np1 : np0;
    const int nrows = nptr ? *nptr : (sector ? ns1 : ns0);
    if (nrows <= 0) return;
    const __bf16* BT = Bt + (size_t)(sector ? 256 : 0) * K;
    const float* bs = bias + (sector ? 256 : 0);
    const int ntiles = (nrows + 127) >> 7;
    const int NT = K >> 5;                       // K-steps: 32 (layer0) / 4 (layer1), always even

    const int tid = threadIdx.x;
    const int lane = tid & 63, wid = tid >> 6;   // wid 0..7
    const int wm = wid >> 2, wn = wid & 3;       // 2 x 4 wave grid
    const int fr = lane & 15, quad = lane >> 4;
    const int rr = tid >> 2;                     // 0..127 B-staging row
    const int swch = (((tid & 3) ^ (rr & 3)) << 3);  // B-staging swizzled chunk (elements)
    const int qsw8 = ((quad ^ (fr & 3)) << 3);       // B fragment-read chunk (elements)

    // B global source: pre-swizzled chunk so the linear gl_lds dest realizes the
    // swizzled layout (element (row,kc) lives at chunk kc ^ (row&3)).
    const __bf16* gB = BT + (size_t)rr * K + swch;

#define GSTEP(kk, afc, afn)                                                                   \
    {                                                                                         \
        const __bf16* Bs = &Bsl[(kk) % 3][0];                                                 \
        _Pragma("unroll")                                                                     \
        for (int ni = 0; ni < 4; ni++) {                                                      \
            bf16x8 b8 = *(const bf16x8*)&Bs[(wn * 64 + ni * 16 + fr) * 32 + qsw8];            \
            _Pragma("unroll")                                                                 \
            for (int mi = 0; mi < 4; mi++)                                                    \
                acc[mi][ni] = __builtin_amdgcn_mfma_f32_16x16x32_bf16(afc[mi], b8,            \
                                                                     acc[mi][ni], 0, 0, 0);   \
        }                                                                                     \
        _Pragma("unroll")                                                                     \
        for (int mi = 0; mi < 4; mi++) afn[mi] = cvtA<AT>(rawA[mi]);                          \
        const int kc = ((kk) + 2 < NT) ? (((kk) + 2) << 5) : ((NT - 1) << 5);                 \
        _Pragma("unroll")                                                                     \
        for (int mi = 0; mi < 4; mi++) loadAraw(aptr[mi] + kc, rawA[mi]);                     \
        __bf16* bd = &Bsl[((kk) + 2) % 3][(size_t)(wid << 4) * 32];                           \
        gl_lds16(gB + kc, bd);                                                                \
        gl_lds16(gB + (size_t)128 * K + kc, bd + 128 * 32);                                   \
        if constexpr (sizeof(AT) == 4)                                                        \
            asm volatile("s_waitcnt vmcnt(10)" ::: "memory");                                 \
        else                                                                                  \
            asm volatile("s_waitcnt vmcnt(6)" ::: "memory");                                  \
        __builtin_amdgcn_s_barrier();                                                         \
    }

    for (int mt = tile0; mt < ntiles; mt += tstr) {
        const int mbase = mt << 7;

        // per-lane A fragment row pointers (4 rows per lane, fixed over K)
        const AT* aptr[4];
#pragma unroll
        for (int mi = 0; mi < 4; mi++) {
            int lr2 = mbase + wm * 64 + mi * 16 + fr;
            if (lr2 >= nrows) lr2 = nrows - 1;
            int g2 = rowlist ? rowlist[lr2] : lr2;
            aptr[mi] = A + (size_t)g2 * K + quad * 8;
        }

        f32x4 acc[4][4];
#pragma unroll
        for (int i = 0; i < 4; i++)
#pragma unroll
            for (int j = 0; j < 4; j++) acc[i][j] = (f32x4){0.f, 0.f, 0.f, 0.f};

        __syncthreads();   // LDS reuse guard across mt iterations (rare multi-tile blocks)

        ARaw<AT> rawA[4];
        bf16x8 afA[4], afB[4];

        // ---- prologue: A(0) -> regs+cvt, B(0) staged; A(1)/B(1) left in flight
        {
#pragma unroll
            for (int mi = 0; mi < 4; mi++) loadAraw(aptr[mi], rawA[mi]);
            __bf16* bd0 = &Bsl[0][(size_t)(wid << 4) * 32];
            gl_lds16(gB, bd0);
            gl_lds16(gB + (size_t)128 * K, bd0 + 128 * 32);
#pragma unroll
            for (int mi = 0; mi < 4; mi++) afA[mi] = cvtA<AT>(rawA[mi]);  // compiler waits A(0)
#pragma unroll
            for (int mi = 0; mi < 4; mi++) loadAraw(aptr[mi] + 32, rawA[mi]);
            __bf16* bd1 = &Bsl[1][(size_t)(wid << 4) * 32];
            gl_lds16(gB + 32, bd1);
            gl_lds16(gB + (size_t)128 * K + 32, bd1 + 128 * 32);
            // drain B(0): everything older than the 10|6 just-issued ops
            if constexpr (sizeof(AT) == 4)
                asm volatile("s_waitcnt vmcnt(10)" ::: "memory");
            else
                asm volatile("s_waitcnt vmcnt(6)" ::: "memory");
            __builtin_amdgcn_s_barrier();
        }

        // ---- pipelined K-loop (NT even; named af sets, no runtime reg indexing)
        for (int kk = 0; kk < NT; kk += 2) {
            GSTEP(kk, afA, afB)
            GSTEP(kk + 1, afB, afA)
        }

        // ---- epilogue
#pragma unroll
        for (int mi = 0; mi < 4; mi++)
#pragma unroll
            for (int ni = 0; ni < 4; ni++) {
                int rl = wm * 64 + mi * 16 + quad * 4;
                int cl = wn * 64 + ni * 16 + fr;
                float b = bs[cl];
#pragma unroll
                for (int r = 0; r < 4; r++) {
                    int lr2 = mbase + rl + r;
                    if (lr2 < nrows) {
                        int gr2 = rowlist ? rowlist[lr2] : lr2;
                        float v = acc[mi][ni][r] + b;
                        if (sector == 0) outb[(size_t)gr2 * 256 + cl] = (__bf16)v;
                        else             outf[(size_t)gr2 * 256 + cl] = v;
                    }
                }
            }
    }
#undef GSTEP
}

// ---------------------------------------------------------------- per-dst online-softmax attention
// q,s f32 from qs[node][0:128 / 128:256]; k,v bf16 from kvb[src][0:128 / 128:256].
// mode 1: out = relu(agg+s) bf16 by node ; mode 0: out f32 by slot.
__global__ __launch_bounds__(256) void attn_kernel(const float* __restrict__ qs,
                                                   const __bf16* __restrict__ kvb,
                                                   const int* __restrict__ off,
                                                   const int* __restrict__ srcs,
                                                   const int* __restrict__ nodelist,
                                                   const int* __restrict__ nptr, int nstatic,
                                                   __bf16* __restrict__ outb,
                                                   float* __restrict__ outf, int mode) {
    int n = nptr ? *nptr : nstatic;
    int lane = threadIdx.x & 63;
    int w0 = blockIdx.x * 4 + (threadIdx.x >> 6);
    int nw = gridDim.x * 4;
    const float scale = 0.08838834764831845f;  // 1/sqrt(128)
    for (int w = w0; w < n; w += nw) {
        int node = nodelist ? nodelist[w] : w;
        const float* bq = qs + (size_t)node * 256;
        float2 q = *(const float2*)(bq + 2 * lane);
        float2 s = *(const float2*)(bq + 128 + 2 * lane);
        int e0 = off[node], e1 = off[node + 1];
        float m = -INFINITY, l = 0.f;
        float ax = 0.f, ay = 0.f;
        bf16x2 kc = {(__bf16)0.f, (__bf16)0.f}, vc = kc;
        if (e0 < e1) {
            const __bf16* p = kvb + (size_t)srcs[e0] * 256;
            kc = *(const bf16x2*)(p + 2 * lane);
            vc = *(const bf16x2*)(p + 128 + 2 * lane);
        }
        for (int e = e0; e < e1; ++e) {
            bf16x2 kn = {(__bf16)0.f, (__bf16)0.f}, vn = kn;
            if (e + 1 < e1) {  // prefetch next edge before the serial chain
                const __bf16* p = kvb + (size_t)srcs[e + 1] * 256;
                kn = *(const bf16x2*)(p + 2 * lane);
                vn = *(const bf16x2*)(p + 128 + 2 * lane);
            }
            float t = q.x * (float)kc.x + q.y * (float)kc.y;
#pragma unroll
            for (int o = 32; o > 0; o >>= 1) t += __shfl_xor(t, o, 64);
            float sc = t * scale;
            float mn = fmaxf(m, sc);
            float al = __expf(m - mn);
            float ee = __expf(sc - mn);
            ax = ax * al + ee * (float)vc.x;
            ay = ay * al + ee * (float)vc.y;
            l = l * al + ee;
            m = mn;
            kc = kn; vc = vn;
        }
        float inv = 1.f / (l + 1e-16f);
        float ox = ax * inv + s.x, oy = ay * inv + s.y;
        if (mode) {
            bf16x2 o2 = {(__bf16)fmaxf(ox, 0.f), (__bf16)fmaxf(oy, 0.f)};
            *(bf16x2*)(outb + (size_t)node * 128 + 2 * lane) = o2;
        } else {
            float2 o2 = {fmaxf(ox, 0.f), fmaxf(oy, 0.f)};
            *(float2*)(outf + (size_t)w * 128 + 2 * lane) = o2;
        }
    }
}

// ---------------------------------------------------------------- MLP head: 128 -> 128 -> 64 -> 1 sigmoid
__global__ __launch_bounds__(128) void mlp_kernel(const float* __restrict__ hbuf,
                                                  const float* __restrict__ mw1, const float* __restrict__ mb1,
                                                  const float* __restrict__ mw2, const float* __restrict__ mb2,
                                                  const float* __restrict__ mw3, const float* __restrict__ mb3,
                                                  float* __restrict__ out, int B) {
    int b = blockIdx.x;
    int t = threadIdx.x;
    if (b >= B) return;
    __shared__ float xr[128], z1[128], z2[64];
    xr[t] = hbuf[(size_t)b * 128 + t];
    __syncthreads();
    float a1 = mb1[t];
#pragma unroll 8
    for (int k = 0; k < 128; ++k) a1 += xr[k] * mw1[k * 128 + t];
    z1[t] = fmaxf(a1, 0.f);
    __syncthreads();
    if (t < 64) {
        float a2 = mb2[t];
#pragma unroll 8
        for (int k = 0; k < 128; ++k) a2 += z1[k] * mw2[k * 64 + t];
        z2[t] = fmaxf(a2, 0.f);
    }
    __syncthreads();
    if (t < 64) {
        float p = z2[t] * mw3[t];
#pragma unroll
        for (int o = 32; o > 0; o >>= 1) p += __shfl_xor(p, o, 64);
        if (t == 0) out[b] = 1.f / (1.f + __expf(-(p + mb3[0])));
    }
}

// ---------------------------------------------------------------- launch
extern "C" void kernel_launch(void* const* d_in, const int* in_sizes, int n_in,
                              void* d_out, int out_size, void* d_ws, size_t ws_size,
                              hipStream_t stream) {
    const float* x   = (const float*)d_in[0];
    const int*   ei  = (const int*)d_in[1];
    const int*   idx = (const int*)d_in[2];
    const float* wq0 = (const float*)d_in[3];
    const float* wk0 = (const float*)d_in[4];
    const float* wv0 = (const float*)d_in[5];
    const float* ws0 = (const float*)d_in[6];
    const float* bq0 = (const float*)d_in[7];
    const float* bk0 = (const float*)d_in[8];
    const float* bv0 = (const float*)d_in[9];
    const float* bs0 = (const float*)d_in[10];
    const float* wq1 = (const float*)d_in[11];
    const float* wk1 = (const float*)d_in[12];
    const float* wv1 = (const float*)d_in[13];
    const float* ws1 = (const float*)d_in[14];
    const float* bq1 = (const float*)d_in[15];
    const float* bk1 = (const float*)d_in[16];
    const float* bv1 = (const float*)d_in[17];
    const float* bs1 = (const float*)d_in[18];
    const float* mw1 = (const float*)d_in[19];
    const float* mb1 = (const float*)d_in[20];
    const float* mw2 = (const float*)d_in[21];
    const float* mb2 = (const float*)d_in[22];
    const float* mw3 = (const float*)d_in[23];
    const float* mb3 = (const float*)d_in[24];
    float* out = (float*)d_out;

    const int Nn = in_sizes[0] / 1024;  // 50000
    const int E  = in_sizes[1] / 2;     // 600000
    const int B  = in_sizes[2];         // 1000
    const int* esrc = ei;
    const int* edst = ei + E;
    const int degPad = ((Nn + 8191) >> 13) << 13;

    uintptr_t base = (uintptr_t)d_ws;
    auto alloc = [&](size_t bytes) -> void* {
        uintptr_t p = (base + 255) & ~(uintptr_t)255;
        base = p + bytes;
        return (void*)p;
    };
    __bf16* kvb  = (__bf16*)alloc((size_t)Nn * 256 * 2);   // 25.6 MB; kv1b aliases (kv0 dead after attn0)
    __bf16* kv1b = kvb;
    float*  qs   = (float*)alloc((size_t)Nn * 256 * 4);    // 51.2 MB; qs1 aliases
    float*  qs1  = qs;
    __bf16* h0b  = (__bf16*)alloc((size_t)Nn * 128 * 2);   // 12.8 MB (only U rows valid)
    float*  hbuf = (float*)alloc((size_t)B * 128 * 4);
    __bf16* w0t  = (__bf16*)alloc(512 * 1024 * 2);
    __bf16* w1t  = (__bf16*)alloc(512 * 128 * 2);
    float*  b0   = (float*)alloc(512 * 4);
    float*  b1   = (float*)alloc(512 * 4);
    // zero region (one memset): deg(padded), cursor, flagIdx, flagU, nU
    int* deg     = (int*)alloc((size_t)degPad * 4);
    int* cursor  = (int*)alloc((size_t)Nn * 4);
    int* flagIdx = (int*)alloc((size_t)Nn * 4);
    int* flagU   = (int*)alloc((size_t)Nn * 4);
    int* nU      = (int*)alloc(256);
    size_t zbytes = (uintptr_t)nU + 256 - (uintptr_t)deg;
    int* off     = (int*)alloc((size_t)(Nn + 1) * 4);
    int* srcs    = (int*)alloc((size_t)E * 4);
    int* U       = (int*)alloc((size_t)Nn * 4);

    hipMemsetAsync(deg, 0, zbytes, stream);

    // ---- U set + CSR
    mark_idx_kernel<<<(B + 255) / 256, 256, 0, stream>>>(idx, flagIdx, flagU, B);
    hist_mark_kernel<<<(E + 255) / 256, 256, 0, stream>>>(esrc, edst, flagIdx, deg, flagU, E);
    scan8_kernel<<<1, 1024, 0, stream>>>(deg, off, Nn, flagU, U, nU);
    scatter_kernel<<<(E + 255) / 256, 256, 0, stream>>>(esrc, edst, off, cursor, srcs, E);

    // ---- weights
    pack_w_kernel<<<(512 * 1024 + 512 * 128 + 1024 + 255) / 256, 256, 0, stream>>>(
        wq0, wk0, wv0, ws0, wq1, wk1, wv1, ws1,
        bq0, bk0, bv0, bs0, bq1, bk1, bv1, bs1, w0t, w1t, b0, b1);

    const int mtiles = (Nn + 127) / 128;  // 391

    // ---- layer 0: sector0 = k|v all rows -> kvb(bf16); sector1 = q|s U rows -> qs(f32)
    // grid: 391 sector0 blocks (1 tile each) + 121 sector1 blocks (grid-stride) = 512, all live
    gemm_dual_kernel<float><<<mtiles + 121, 512, 0, stream>>>(x, w0t, b0, kvb, qs,
                                                              nullptr, nullptr, Nn,
                                                              U, nU, 0, 1024, mtiles);
    attn_kernel<<<4096, 256, 0, stream>>>(qs, kvb, off, srcs, U, nU, 0, h0b, nullptr, 1);

    // ---- layer 1: sector0 = k|v U rows -> kv1b(bf16); sector1 = q|s idx rows -> qs1(f32)
    gemm_dual_kernel<__bf16><<<144, 512, 0, stream>>>(h0b, w1t, b1, kv1b, qs1,
                                                      U, nU, 0,
                                                      idx, nullptr, B, 128, 128);
    attn_kernel<<<(B + 3) / 4, 256, 0, stream>>>(qs1, kv1b, off, srcs, idx, nullptr, B, nullptr, hbuf, 0);

    // ---- MLP head
    mlp_kernel<<<B, 128, 0, stream>>>(hbuf, mw1, mb1, mw2, mb2, mw3, mb3, out, B);
}

// Round 6
// 549.132 us; speedup vs baseline: 1.2493x; 1.2493x over previous
//
#include <hip/hip_runtime.h>
#include <hip/hip_bf16.h>
#include <cstdint>
#include <cstddef>

typedef __bf16 bf16x2 __attribute__((ext_vector_type(2)));
typedef __bf16 bf16x8 __attribute__((ext_vector_type(8)));
typedef float f32x4 __attribute__((ext_vector_type(4)));

__device__ __forceinline__ void gl_lds16(const __bf16* g, __bf16* l) {
    __builtin_amdgcn_global_load_lds(
        (const __attribute__((address_space(1))) unsigned int*)g,
        (__attribute__((address_space(3))) unsigned int*)l, 16, 0, 0);
}

// raw (unconverted) A registers: defer f32->bf16 cvt to the ds_write site so the
// vmcnt wait for the loads lands at the consumer, not at issue (keeps pipeline deep).
template <typename AT> struct ARaw;
template <> struct ARaw<float>  { float4 u, v; };
template <> struct ARaw<__bf16> { bf16x8 w; };

template <typename AT>
__device__ __forceinline__ void loadAraw(const AT* p, ARaw<AT>& r) {
    if constexpr (sizeof(AT) == 4) {
        r.u = *(const float4*)p;
        r.v = *(const float4*)(p + 4);
    } else {
        r.w = *(const bf16x8*)p;
    }
}

template <typename AT>
__device__ __forceinline__ bf16x8 cvtA(const ARaw<AT>& r) {
    if constexpr (sizeof(AT) == 4) {
        return (bf16x8){(__bf16)r.u.x, (__bf16)r.u.y, (__bf16)r.u.z, (__bf16)r.u.w,
                        (__bf16)r.v.x, (__bf16)r.v.y, (__bf16)r.v.z, (__bf16)r.v.w};
    } else {
        return r.w;
    }
}

// ---------------------------------------------------------------- U-set marking
__global__ __launch_bounds__(256) void mark_idx_kernel(const int* __restrict__ idx,
                                                       int* __restrict__ flagIdx,
                                                       int* __restrict__ flagU, int B) {
    int t = blockIdx.x * 256 + threadIdx.x;
    if (t < B) {
        int n = idx[t];
        flagIdx[n] = 1;
        flagU[n] = 1;
    }
}

// histogram of dst + mark sources of idx-edges (one pass over edges)
__global__ __launch_bounds__(256) void hist_mark_kernel(const int* __restrict__ esrc,
                                                        const int* __restrict__ edst,
                                                        const int* __restrict__ flagIdx,
                                                        int* __restrict__ deg,
                                                        int* __restrict__ flagU, int E) {
    int e = blockIdx.x * 256 + threadIdx.x;
    if (e < E) {
        int d = edst[e];
        atomicAdd(&deg[d], 1);
        if (flagIdx[d]) flagU[esrc[e]] = 1;
    }
}

// ---------------------------------------------------------------- scan (1 block, 8/thread) + U-compaction tail
__global__ __launch_bounds__(1024) void scan8_kernel(const int* __restrict__ deg,
                                                     int* __restrict__ off, int n,
                                                     const int* __restrict__ flagU,
                                                     int* __restrict__ U,
                                                     int* __restrict__ nU) {
    __shared__ int wsum[16];
    int tid = threadIdx.x, lane = tid & 63, wid = tid >> 6;
    if (tid == 0) off[0] = 0;
    int carry = 0;
    int nchunk = (n + 8191) >> 13;
    for (int c = 0; c < nchunk; ++c) {
        int base = (c << 13) + tid * 8;
        int4 a = *(const int4*)(deg + base);
        int4 b = *(const int4*)(deg + base + 4);
        int s[8];
        s[0] = a.x; s[1] = s[0] + a.y; s[2] = s[1] + a.z; s[3] = s[2] + a.w;
        s[4] = s[3] + b.x; s[5] = s[4] + b.y; s[6] = s[5] + b.z; s[7] = s[6] + b.w;
        int x = s[7];
        for (int o = 1; o < 64; o <<= 1) {
            int t = __shfl_up(x, o, 64);
            if (lane >= o) x += t;
        }
        if (lane == 63) wsum[wid] = x;
        __syncthreads();
        if (wid == 0 && lane < 16) {
            int w = wsum[lane];
            for (int o = 1; o < 16; o <<= 1) {
                int t = __shfl_up(w, o, 64);
                if (lane >= o) w += t;
            }
            wsum[lane] = w;
        }
        __syncthreads();
        int pre = carry + (wid ? wsum[wid - 1] : 0) + (x - s[7]);
#pragma unroll
        for (int i = 0; i < 8; ++i)
            if (base + i < n) off[base + i + 1] = pre + s[i];
        carry += wsum[15];
        __syncthreads();
    }
    // fused U-compaction (independent of the scan, needs only flagU)
    for (int i = tid; i < n; i += 1024)
        if (flagU[i]) U[atomicAdd(nU, 1)] = i;
}

__global__ __launch_bounds__(256) void scatter_kernel(const int* __restrict__ src,
                                                      const int* __restrict__ dst,
                                                      const int* __restrict__ off,
                                                      int* __restrict__ cursor,
                                                      int* __restrict__ srcs, int E) {
    int e = blockIdx.x * 256 + threadIdx.x;
    if (e < E) {
        int d = dst[e];
        int p = off[d] + atomicAdd(&cursor[d], 1);
        srcs[p] = src[e];
    }
}

// ---------------------------------------------------------------- weight prep
// w0t: [512,1024] bf16 rows ordered k,v,q,s ; w1t: [512,128] ; b0,b1: [512] f32 same order
__global__ __launch_bounds__(256) void pack_w_kernel(const float* __restrict__ wq0, const float* __restrict__ wk0,
                                                     const float* __restrict__ wv0, const float* __restrict__ ws0,
                                                     const float* __restrict__ wq1, const float* __restrict__ wk1,
                                                     const float* __restrict__ wv1, const float* __restrict__ ws1,
                                                     const float* __restrict__ bq0, const float* __restrict__ bk0,
                                                     const float* __restrict__ bv0, const float* __restrict__ bs0,
                                                     const float* __restrict__ bq1, const float* __restrict__ bk1,
                                                     const float* __restrict__ bv1, const float* __restrict__ bs1,
                                                     __bf16* __restrict__ w0t, __bf16* __restrict__ w1t,
                                                     float* __restrict__ b0, float* __restrict__ b1) {
    int i = blockIdx.x * 256 + threadIdx.x;
    const int S0 = 512 * 1024, S1 = 512 * 128;
    if (i < S0) {
        int n = i >> 10, k = i & 1023;
        int sel = n >> 7, c = n & 127;
        const float* w = (sel == 0) ? wk0 : (sel == 1) ? wv0 : (sel == 2) ? wq0 : ws0;
        w0t[i] = (__bf16)w[(size_t)k * 128 + c];
    } else if (i < S0 + S1) {
        int j = i - S0;
        int n = j >> 7, k = j & 127;
        int sel = n >> 7, c = n & 127;
        const float* w = (sel == 0) ? wk1 : (sel == 1) ? wv1 : (sel == 2) ? wq1 : ws1;
        w1t[j] = (__bf16)w[(size_t)k * 128 + c];
    } else if (i < S0 + S1 + 512) {
        int t = i - S0 - S1;
        int sel = t >> 7, c = t & 127;
        const float* b = (sel == 0) ? bk0 : (sel == 1) ? bv0 : (sel == 2) ? bq0 : bs0;
        b0[t] = b[c];
    } else if (i < S0 + S1 + 1024) {
        int t = i - S0 - S1 - 512;
        int sel = t >> 7, c = t & 127;
        const float* b = (sel == 0) ? bk1 : (sel == 1) ? bv1 : (sel == 2) ? bq1 : bs1;
        b1[t] = b[c];
    }
}

// ---------------------------------------------------------------- dual-sector MFMA GEMM
// R10 = exact R7 revert (best measured: gemm0 ~111us). A staged through LDS with
// coalesced loads (R9's direct-to-reg gather fragmented VMEM transactions, -2x).
// 1-D all-live balanced grid + counted-wait 2-deep pipeline (no vmcnt(0) in loop).
// blockIdx.x <  s0blocks -> sector 0: Bt rows [0,256)   -> outb (bf16), rows rl0/n0
// blockIdx.x >= s0blocks -> sector 1: Bt rows [256,512) -> outf (f32),  rows rl1/n1
// Block tile 128(M) x 256(N), BK=32. 512 threads = 8 waves (2m x 4n), wave tile 64x64.
// B: triple-buffered LDS via global_load_lds (prefetch dist 2). A: reg-staged (raw,
// cvt deferred to ds_write), double-buffered LDS. Raw s_barrier with lgkmcnt(0) only;
// the A-ds_write's compiler-inserted vmcnt is a counted wait (2 gl_lds of tile k+2
// pending) -> loads span a full step + barrier.
template <typename AT>
__global__ __launch_bounds__(512, 4) void gemm_dual_kernel(const AT* __restrict__ A,
                                                           const __bf16* __restrict__ Bt,
                                                           const float* __restrict__ bias,
                                                           __bf16* __restrict__ outb,
                                                           float* __restrict__ outf,
                                                           const int* __restrict__ rl0,
                                                           const int* __restrict__ np0, int ns0,
                                                           const int* __restrict__ rl1,
                                                           const int* __restrict__ np1, int ns1,
                                                           int K, int s0blocks) {
    __shared__ __align__(16) __bf16 Asl[2][128 * 32];   // 16 KB
    __shared__ __align__(16) __bf16 Bsl[3][256 * 32];   // 48 KB
    const int bx = blockIdx.x;
    const int sector = (bx >= s0blocks) ? 1 : 0;
    const int tile0  = sector ? bx - s0blocks : bx;
    const int tstr   = sector ? (gridDim.x - s0blocks) : s0blocks;
    const int* rowlist = sector ? rl1 : rl0;
    const int* nptr = sector ? np1 : np0;
    const int nrows = nptr ? *nptr : (sector ? ns1 : ns0);
    if (nrows <= 0) return;
    const __bf16* BT = Bt + (size_t)(sector ? 256 : 0) * K;
    const float* bs = bias + (sector ? 256 : 0);
    const int ntiles = (nrows + 127) >> 7;
    const int NT = K >> 5;                       // K-steps (32 for layer0, 4 for layer1)

    const int tid = threadIdx.x;
    const int lane = tid & 63, wid = tid >> 6;   // wid 0..7
    const int wm = wid >> 2, wn = wid & 3;       // 2 x 4 wave grid
    const int fr = lane & 15, quad = lane >> 4;
    const int rr = tid >> 2;                     // 0..127 staging row
    const int kc8 = (tid & 3) << 3;              // A global k-offset (coalesced, unswizzled)
    const int swch = (((tid & 3) ^ (rr & 3)) << 3);  // swizzled chunk offset (elements)
    const int qsw8 = ((quad ^ (fr & 3)) << 3);       // fragment-read chunk offset (elements)

    // B global source: pre-swizzled chunk so the linear gl_lds dest realizes the
    // swizzled layout (element (row,kc) lives at chunk kc ^ (row&3)).
    const __bf16* gB = BT + (size_t)rr * K + swch;

    for (int mt = tile0; mt < ntiles; mt += tstr) {
        const int mbase = mt << 7;
        int lr = mbase + rr;
        if (lr >= nrows) lr = nrows - 1;
        const int gr = rowlist ? rowlist[lr] : lr;
        const AT* gA = A + (size_t)gr * K + kc8;

        f32x4 acc[4][4];
#pragma unroll
        for (int i = 0; i < 4; i++)
#pragma unroll
            for (int j = 0; j < 4; j++) acc[i][j] = (f32x4){0.f, 0.f, 0.f, 0.f};

        __syncthreads();   // LDS reuse guard across mt iterations (full drain, once per tile)

        // ---- prologue: stage tiles 0 and 1
        ARaw<AT> a0, aC;
        {
            __bf16* bd0 = &Bsl[0][(size_t)(wid << 4) * 32];
            gl_lds16(gB, bd0);
            gl_lds16(gB + (size_t)128 * K, bd0 + 128 * 32);
            loadAraw(gA, a0);
            __bf16* bd1 = &Bsl[1][(size_t)(wid << 4) * 32];
            gl_lds16(gB + 32, bd1);
            gl_lds16(gB + (size_t)128 * K + 32, bd1 + 128 * 32);
            loadAraw(gA + 32, aC);
            // compiler inserts counted vmcnt here (a0 use; B1/A1 still in flight)
            *(bf16x8*)&Asl[0][rr * 32 + swch] = cvtA<AT>(a0);
            asm volatile("s_waitcnt lgkmcnt(0)" ::: "memory");
            __builtin_amdgcn_s_barrier();   // B0 already drained by the a0-wait above
        }

        // ---- pipelined K-loop
        for (int k = 0; k < NT; ++k) {
            const __bf16* As = Asl[k & 1];
            const __bf16* Bs = Bsl[k % 3];
            bf16x8 af[4];
#pragma unroll
            for (int mi = 0; mi < 4; mi++)
                af[mi] = *(const bf16x8*)&As[(wm * 64 + mi * 16 + fr) * 32 + qsw8];
#pragma unroll
            for (int ni = 0; ni < 4; ni++) {
                bf16x8 b8 = *(const bf16x8*)&Bs[(wn * 64 + ni * 16 + fr) * 32 + qsw8];
#pragma unroll
                for (int mi = 0; mi < 4; mi++)
                    acc[mi][ni] = __builtin_amdgcn_mfma_f32_16x16x32_bf16(af[mi], b8, acc[mi][ni], 0, 0, 0);
            }
            const bool wr = (k + 1 < NT);
            const bool pf = (k + 2 < NT);
            if (pf) {   // issue B(k+2) gl_lds first (no dest regs)
                const int kn = (k + 2) << 5;
                __bf16* bd = &Bsl[(k + 2) % 3][(size_t)(wid << 4) * 32];
                gl_lds16(gB + kn, bd);
                gl_lds16(gB + (size_t)128 * K + kn, bd + 128 * 32);
            }
            if (wr) {
                // consume aC = A(k+1): compiler waits vmcnt(2) (only the 2 new gl_lds pending)
                // -> also guarantees B(k+1) landed before the barrier below.
                *(bf16x8*)&Asl[(k + 1) & 1][rr * 32 + swch] = cvtA<AT>(aC);
            }
            if (pf) {   // reload aC with A(k+2) (regs dead after the write above)
                loadAraw(gA + ((k + 2) << 5), aC);
            }
            if (wr) {
                asm volatile("s_waitcnt lgkmcnt(0)" ::: "memory");
                __builtin_amdgcn_s_barrier();
            }
        }

        // ---- epilogue
#pragma unroll
        for (int mi = 0; mi < 4; mi++)
#pragma unroll
            for (int ni = 0; ni < 4; ni++) {
                int rl = wm * 64 + mi * 16 + quad * 4;
                int cl = wn * 64 + ni * 16 + fr;
                float b = bs[cl];
#pragma unroll
                for (int r = 0; r < 4; r++) {
                    int lr2 = mbase + rl + r;
                    if (lr2 < nrows) {
                        int gr2 = rowlist ? rowlist[lr2] : lr2;
                        float v = acc[mi][ni][r] + b;
                        if (sector == 0) outb[(size_t)gr2 * 256 + cl] = (__bf16)v;
                        else             outf[(size_t)gr2 * 256 + cl] = v;
                    }
                }
            }
    }
}

// ---------------------------------------------------------------- per-dst online-softmax attention (layer 0)
// q,s f32 from qs[node][0:128 / 128:256]; k,v bf16 from kvb[src][0:128 / 128:256].
// out = relu(agg+s) bf16 by node.
__global__ __launch_bounds__(256) void attn_kernel(const float* __restrict__ qs,
                                                   const __bf16* __restrict__ kvb,
                                                   const int* __restrict__ off,
                                                   const int* __restrict__ srcs,
                                                   const int* __restrict__ nodelist,
                                                   const int* __restrict__ nptr, int nstatic,
                                                   __bf16* __restrict__ outb) {
    int n = nptr ? *nptr : nstatic;
    int lane = threadIdx.x & 63;
    int w0 = blockIdx.x * 4 + (threadIdx.x >> 6);
    int nw = gridDim.x * 4;
    const float scale = 0.08838834764831845f;  // 1/sqrt(128)
    for (int w = w0; w < n; w += nw) {
        int node = nodelist ? nodelist[w] : w;
        const float* bq = qs + (size_t)node * 256;
        float2 q = *(const float2*)(bq + 2 * lane);
        float2 s = *(const float2*)(bq + 128 + 2 * lane);
        int e0 = off[node], e1 = off[node + 1];
        float m = -INFINITY, l = 0.f;
        float ax = 0.f, ay = 0.f;
        bf16x2 kc = {(__bf16)0.f, (__bf16)0.f}, vc = kc;
        if (e0 < e1) {
            const __bf16* p = kvb + (size_t)srcs[e0] * 256;
            kc = *(const bf16x2*)(p + 2 * lane);
            vc = *(const bf16x2*)(p + 128 + 2 * lane);
        }
        for (int e = e0; e < e1; ++e) {
            bf16x2 kn = {(__bf16)0.f, (__bf16)0.f}, vn = kn;
            if (e + 1 < e1) {  // prefetch next edge before the serial chain
                const __bf16* p = kvb + (size_t)srcs[e + 1] * 256;
                kn = *(const bf16x2*)(p + 2 * lane);
                vn = *(const bf16x2*)(p + 128 + 2 * lane);
            }
            float t = q.x * (float)kc.x + q.y * (float)kc.y;
#pragma unroll
            for (int o = 32; o > 0; o >>= 1) t += __shfl_xor(t, o, 64);
            float sc = t * scale;
            float mn = fmaxf(m, sc);
            float al = __expf(m - mn);
            float ee = __expf(sc - mn);
            ax = ax * al + ee * (float)vc.x;
            ay = ay * al + ee * (float)vc.y;
            l = l * al + ee;
            m = mn;
            kc = kn; vc = vn;
        }
        float inv = 1.f / (l + 1e-16f);
        float ox = ax * inv + s.x, oy = ay * inv + s.y;
        bf16x2 o2 = {(__bf16)fmaxf(ox, 0.f), (__bf16)fmaxf(oy, 0.f)};
        *(bf16x2*)(outb + (size_t)node * 128 + 2 * lane) = o2;
    }
}

// ---------------------------------------------------------------- fused layer-1 attention + MLP head
// One wave per graph b: online-softmax over idx[b]'s in-edges -> h = relu(agg+s)
// kept in a per-wave LDS strip, then 128->128->64->1 head inline (64 lanes = layer
// widths; z2 output t == lane). Removes the mlp launch + hbuf HBM round-trip.
__global__ __launch_bounds__(256) void attn_mlp_kernel(const float* __restrict__ qs,
                                                       const __bf16* __restrict__ kvb,
                                                       const int* __restrict__ off,
                                                       const int* __restrict__ srcs,
                                                       const int* __restrict__ idx,
                                                       const float* __restrict__ mw1, const float* __restrict__ mb1,
                                                       const float* __restrict__ mw2, const float* __restrict__ mb2,
                                                       const float* __restrict__ mw3, const float* __restrict__ mb3,
                                                       float* __restrict__ out, int B) {
    __shared__ float hl[4][128];
    __shared__ float z1l[4][128];
    int lane = threadIdx.x & 63;
    int ws = threadIdx.x >> 6;
    int w = blockIdx.x * 4 + ws;
    if (w >= B) return;
    int node = idx[w];
    const float scale = 0.08838834764831845f;  // 1/sqrt(128)
    const float* bq = qs + (size_t)node * 256;
    float2 q = *(const float2*)(bq + 2 * lane);
    float2 s = *(const float2*)(bq + 128 + 2 * lane);
    int e0 = off[node], e1 = off[node + 1];
    float m = -INFINITY, l = 0.f;
    float ax = 0.f, ay = 0.f;
    bf16x2 kc = {(__bf16)0.f, (__bf16)0.f}, vc = kc;
    if (e0 < e1) {
        const __bf16* p = kvb + (size_t)srcs[e0] * 256;
        kc = *(const bf16x2*)(p + 2 * lane);
        vc = *(const bf16x2*)(p + 128 + 2 * lane);
    }
    for (int e = e0; e < e1; ++e) {
        bf16x2 kn = {(__bf16)0.f, (__bf16)0.f}, vn = kn;
        if (e + 1 < e1) {
            const __bf16* p = kvb + (size_t)srcs[e + 1] * 256;
            kn = *(const bf16x2*)(p + 2 * lane);
            vn = *(const bf16x2*)(p + 128 + 2 * lane);
        }
        float t = q.x * (float)kc.x + q.y * (float)kc.y;
#pragma unroll
        for (int o = 32; o > 0; o >>= 1) t += __shfl_xor(t, o, 64);
        float sc = t * scale;
        float mn = fmaxf(m, sc);
        float al = __expf(m - mn);
        float ee = __expf(sc - mn);
        ax = ax * al + ee * (float)vc.x;
        ay = ay * al + ee * (float)vc.y;
        l = l * al + ee;
        m = mn;
        kc = kn; vc = vn;
    }
    float inv = 1.f / (l + 1e-16f);
    hl[ws][2 * lane]     = fmaxf(ax * inv + s.x, 0.f);
    hl[ws][2 * lane + 1] = fmaxf(ay * inv + s.y, 0.f);
    // wave-local LDS exchange: drain ds writes before cross-lane reads (no block barrier needed)
    asm volatile("s_waitcnt lgkmcnt(0)" ::: "memory");
    // z1[t] for t = 2*lane, 2*lane+1
    float a0 = mb1[2 * lane], a1 = mb1[2 * lane + 1];
#pragma unroll 8
    for (int k = 0; k < 128; ++k) {
        float hk = hl[ws][k];
        float2 wv = *(const float2*)&mw1[(size_t)k * 128 + 2 * lane];
        a0 += hk * wv.x;
        a1 += hk * wv.y;
    }
    z1l[ws][2 * lane]     = fmaxf(a0, 0.f);
    z1l[ws][2 * lane + 1] = fmaxf(a1, 0.f);
    asm volatile("s_waitcnt lgkmcnt(0)" ::: "memory");
    // z2[lane] (64 outputs == 64 lanes)
    float a2 = mb2[lane];
#pragma unroll 8
    for (int k = 0; k < 128; ++k) a2 += z1l[ws][k] * mw2[(size_t)k * 64 + lane];
    float z2 = fmaxf(a2, 0.f);
    float p = z2 * mw3[lane];
#pragma unroll
    for (int o = 32; o > 0; o >>= 1) p += __shfl_xor(p, o, 64);
    if (lane == 0) out[w] = 1.f / (1.f + __expf(-(p + mb3[0])));
}

// ---------------------------------------------------------------- launch
extern "C" void kernel_launch(void* const* d_in, const int* in_sizes, int n_in,
                              void* d_out, int out_size, void* d_ws, size_t ws_size,
                              hipStream_t stream) {
    const float* x   = (const float*)d_in[0];
    const int*   ei  = (const int*)d_in[1];
    const int*   idx = (const int*)d_in[2];
    const float* wq0 = (const float*)d_in[3];
    const float* wk0 = (const float*)d_in[4];
    const float* wv0 = (const float*)d_in[5];
    const float* ws0 = (const float*)d_in[6];
    const float* bq0 = (const float*)d_in[7];
    const float* bk0 = (const float*)d_in[8];
    const float* bv0 = (const float*)d_in[9];
    const float* bs0 = (const float*)d_in[10];
    const float* wq1 = (const float*)d_in[11];
    const float* wk1 = (const float*)d_in[12];
    const float* wv1 = (const float*)d_in[13];
    const float* ws1 = (const float*)d_in[14];
    const float* bq1 = (const float*)d_in[15];
    const float* bk1 = (const float*)d_in[16];
    const float* bv1 = (const float*)d_in[17];
    const float* bs1 = (const float*)d_in[18];
    const float* mw1 = (const float*)d_in[19];
    const float* mb1 = (const float*)d_in[20];
    const float* mw2 = (const float*)d_in[21];
    const float* mb2 = (const float*)d_in[22];
    const float* mw3 = (const float*)d_in[23];
    const float* mb3 = (const float*)d_in[24];
    float* out = (float*)d_out;

    const int Nn = in_sizes[0] / 1024;  // 50000
    const int E  = in_sizes[1] / 2;     // 600000
    const int B  = in_sizes[2];         // 1000
    const int* esrc = ei;
    const int* edst = ei + E;
    const int degPad = ((Nn + 8191) >> 13) << 13;

    uintptr_t base = (uintptr_t)d_ws;
    auto alloc = [&](size_t bytes) -> void* {
        uintptr_t p = (base + 255) & ~(uintptr_t)255;
        base = p + bytes;
        return (void*)p;
    };
    __bf16* kvb  = (__bf16*)alloc((size_t)Nn * 256 * 2);   // 25.6 MB; kv1b aliases (kv0 dead after attn0)
    __bf16* kv1b = kvb;
    float*  qs   = (float*)alloc((size_t)Nn * 256 * 4);    // 51.2 MB; qs1 aliases
    float*  qs1  = qs;
    __bf16* h0b  = (__bf16*)alloc((size_t)Nn * 128 * 2);   // 12.8 MB (only U rows valid)
    __bf16* w0t  = (__bf16*)alloc(512 * 1024 * 2);
    __bf16* w1t  = (__bf16*)alloc(512 * 128 * 2);
    float*  b0   = (float*)alloc(512 * 4);
    float*  b1   = (float*)alloc(512 * 4);
    // zero region (one memset): deg(padded), cursor, flagIdx, flagU, nU
    int* deg     = (int*)alloc((size_t)degPad * 4);
    int* cursor  = (int*)alloc((size_t)Nn * 4);
    int* flagIdx = (int*)alloc((size_t)Nn * 4);
    int* flagU   = (int*)alloc((size_t)Nn * 4);
    int* nU      = (int*)alloc(256);
    size_t zbytes = (uintptr_t)nU + 256 - (uintptr_t)deg;
    int* off     = (int*)alloc((size_t)(Nn + 1) * 4);
    int* srcs    = (int*)alloc((size_t)E * 4);
    int* U       = (int*)alloc((size_t)Nn * 4);

    hipMemsetAsync(deg, 0, zbytes, stream);

    // ---- U set + CSR
    mark_idx_kernel<<<(B + 255) / 256, 256, 0, stream>>>(idx, flagIdx, flagU, B);
    hist_mark_kernel<<<(E + 255) / 256, 256, 0, stream>>>(esrc, edst, flagIdx, deg, flagU, E);
    scan8_kernel<<<1, 1024, 0, stream>>>(deg, off, Nn, flagU, U, nU);
    scatter_kernel<<<(E + 255) / 256, 256, 0, stream>>>(esrc, edst, off, cursor, srcs, E);

    // ---- weights
    pack_w_kernel<<<(512 * 1024 + 512 * 128 + 1024 + 255) / 256, 256, 0, stream>>>(
        wq0, wk0, wv0, ws0, wq1, wk1, wv1, ws1,
        bq0, bk0, bv0, bs0, bq1, bk1, bv1, bs1, w0t, w1t, b0, b1);

    const int mtiles = (Nn + 127) / 128;  // 391

    // ---- layer 0: sector0 = k|v all rows -> kvb(bf16); sector1 = q|s U rows -> qs(f32)
    // grid: 391 sector0 blocks (1 tile each) + 121 sector1 blocks (grid-stride) = 512, all live
    gemm_dual_kernel<float><<<mtiles + 121, 512, 0, stream>>>(x, w0t, b0, kvb, qs,
                                                              nullptr, nullptr, Nn,
                                                              U, nU, 0, 1024, mtiles);
    attn_kernel<<<4096, 256, 0, stream>>>(qs, kvb, off, srcs, U, nU, 0, h0b);

    // ---- layer 1: sector0 = k|v U rows -> kv1b(bf16); sector1 = q|s idx rows -> qs1(f32)
    gemm_dual_kernel<__bf16><<<144, 512, 0, stream>>>(h0b, w1t, b1, kv1b, qs1,
                                                      U, nU, 0,
                                                      idx, nullptr, B, 128, 128);
    // ---- fused layer-1 attention + MLP head
    attn_mlp_kernel<<<(B + 3) / 4, 256, 0, stream>>>(qs1, kv1b, off, srcs, idx,
                                                     mw1, mb1, mw2, mb2, mw3, mb3, out, B);
}

// Round 8
// 524.139 us; speedup vs baseline: 1.3089x; 1.0477x over previous
//
#include <hip/hip_runtime.h>
#include <hip/hip_bf16.h>
#include <cstdint>
#include <cstddef>

typedef __bf16 bf16x2 __attribute__((ext_vector_type(2)));
typedef __bf16 bf16x8 __attribute__((ext_vector_type(8)));
typedef float f32x4 __attribute__((ext_vector_type(4)));

__device__ __forceinline__ void gl_lds16(const __bf16* g, __bf16* l) {
    __builtin_amdgcn_global_load_lds(
        (const __attribute__((address_space(1))) unsigned int*)g,
        (__attribute__((address_space(3))) unsigned int*)l, 16, 0, 0);
}

// raw (unconverted) A registers: defer f32->bf16 cvt to the ds_write site so the
// vmcnt wait for the loads lands at the consumer, not at issue (keeps pipeline deep).
template <typename AT> struct ARaw;
template <> struct ARaw<float>  { float4 u, v; };
template <> struct ARaw<__bf16> { bf16x8 w; };

template <typename AT>
__device__ __forceinline__ void loadAraw(const AT* p, ARaw<AT>& r) {
    if constexpr (sizeof(AT) == 4) {
        r.u = *(const float4*)p;
        r.v = *(const float4*)(p + 4);
    } else {
        r.w = *(const bf16x8*)p;
    }
}

template <typename AT>
__device__ __forceinline__ bf16x8 cvtA(const ARaw<AT>& r) {
    if constexpr (sizeof(AT) == 4) {
        return (bf16x8){(__bf16)r.u.x, (__bf16)r.u.y, (__bf16)r.u.z, (__bf16)r.u.w,
                        (__bf16)r.v.x, (__bf16)r.v.y, (__bf16)r.v.z, (__bf16)r.v.w};
    } else {
        return r.w;
    }
}

// ---------------------------------------------------------------- U-set marking (byte flags, L2-resident)
__global__ __launch_bounds__(256) void mark_idx_kernel(const int* __restrict__ idx,
                                                       unsigned char* __restrict__ flagIdx,
                                                       unsigned char* __restrict__ flagU, int B) {
    int t = blockIdx.x * 256 + threadIdx.x;
    if (t < B) {
        int n = idx[t];
        flagIdx[n] = 1;
        flagU[n] = 1;
    }
}

// pass 1 over edges: mark sources of idx-edges (no atomics; benign byte-store races)
__global__ __launch_bounds__(256) void mark_src_kernel(const int* __restrict__ esrc,
                                                       const int* __restrict__ edst,
                                                       const unsigned char* __restrict__ flagIdx,
                                                       unsigned char* __restrict__ flagU, int E) {
    int e = blockIdx.x * 256 + threadIdx.x;
    if (e < E) {
        if (flagIdx[edst[e]]) flagU[esrc[e]] = 1;
    }
}

// pass 2 over edges: degree histogram ONLY for dst in U (~26% of edges -> 4x fewer atomics)
__global__ __launch_bounds__(256) void deg_kernel(const int* __restrict__ edst,
                                                  const unsigned char* __restrict__ flagU,
                                                  int* __restrict__ deg, int E) {
    int e = blockIdx.x * 256 + threadIdx.x;
    if (e < E) {
        int d = edst[e];
        if (flagU[d]) atomicAdd(&deg[d], 1);
    }
}

// ---------------------------------------------------------------- scan (1 block, 8/thread) + U-compaction tail
__global__ __launch_bounds__(1024) void scan8_kernel(const int* __restrict__ deg,
                                                     int* __restrict__ off, int n,
                                                     const unsigned char* __restrict__ flagU,
                                                     int* __restrict__ U,
                                                     int* __restrict__ nU) {
    __shared__ int wsum[16];
    int tid = threadIdx.x, lane = tid & 63, wid = tid >> 6;
    if (tid == 0) off[0] = 0;
    int carry = 0;
    int nchunk = (n + 8191) >> 13;
    for (int c = 0; c < nchunk; ++c) {
        int base = (c << 13) + tid * 8;
        int4 a = *(const int4*)(deg + base);
        int4 b = *(const int4*)(deg + base + 4);
        int s[8];
        s[0] = a.x; s[1] = s[0] + a.y; s[2] = s[1] + a.z; s[3] = s[2] + a.w;
        s[4] = s[3] + b.x; s[5] = s[4] + b.y; s[6] = s[5] + b.z; s[7] = s[6] + b.w;
        int x = s[7];
        for (int o = 1; o < 64; o <<= 1) {
            int t = __shfl_up(x, o, 64);
            if (lane >= o) x += t;
        }
        if (lane == 63) wsum[wid] = x;
        __syncthreads();
        if (wid == 0 && lane < 16) {
            int w = wsum[lane];
            for (int o = 1; o < 16; o <<= 1) {
                int t = __shfl_up(w, o, 64);
                if (lane >= o) w += t;
            }
            wsum[lane] = w;
        }
        __syncthreads();
        int pre = carry + (wid ? wsum[wid - 1] : 0) + (x - s[7]);
#pragma unroll
        for (int i = 0; i < 8; ++i)
            if (base + i < n) off[base + i + 1] = pre + s[i];
        carry += wsum[15];
        __syncthreads();
    }
    // fused U-compaction (independent of the scan, needs only flagU)
    for (int i = tid; i < n; i += 1024)
        if (flagU[i]) U[atomicAdd(nU, 1)] = i;
}

__global__ __launch_bounds__(256) void scatter_kernel(const int* __restrict__ src,
                                                      const int* __restrict__ dst,
                                                      const unsigned char* __restrict__ flagU,
                                                      const int* __restrict__ off,
                                                      int* __restrict__ cursor,
                                                      int* __restrict__ srcs, int E) {
    int e = blockIdx.x * 256 + threadIdx.x;
    if (e < E) {
        int d = dst[e];
        if (flagU[d]) {
            int p = off[d] + atomicAdd(&cursor[d], 1);
            srcs[p] = src[e];
        }
    }
}

// ---------------------------------------------------------------- weight prep
// w0t: [512,1024] bf16 rows ordered k,v,q,s ; w1t: [512,128] ; b0,b1: [512] f32 same order
__global__ __launch_bounds__(256) void pack_w_kernel(const float* __restrict__ wq0, const float* __restrict__ wk0,
                                                     const float* __restrict__ wv0, const float* __restrict__ ws0,
                                                     const float* __restrict__ wq1, const float* __restrict__ wk1,
                                                     const float* __restrict__ wv1, const float* __restrict__ ws1,
                                                     const float* __restrict__ bq0, const float* __restrict__ bk0,
                                                     const float* __restrict__ bv0, const float* __restrict__ bs0,
                                                     const float* __restrict__ bq1, const float* __restrict__ bk1,
                                                     const float* __restrict__ bv1, const float* __restrict__ bs1,
                                                     __bf16* __restrict__ w0t, __bf16* __restrict__ w1t,
                                                     float* __restrict__ b0, float* __restrict__ b1) {
    int i = blockIdx.x * 256 + threadIdx.x;
    const int S0 = 512 * 1024, S1 = 512 * 128;
    if (i < S0) {
        int n = i >> 10, k = i & 1023;
        int sel = n >> 7, c = n & 127;
        const float* w = (sel == 0) ? wk0 : (sel == 1) ? wv0 : (sel == 2) ? wq0 : ws0;
        w0t[i] = (__bf16)w[(size_t)k * 128 + c];
    } else if (i < S0 + S1) {
        int j = i - S0;
        int n = j >> 7, k = j & 127;
        int sel = n >> 7, c = n & 127;
        const float* w = (sel == 0) ? wk1 : (sel == 1) ? wv1 : (sel == 2) ? wq1 : ws1;
        w1t[j] = (__bf16)w[(size_t)k * 128 + c];
    } else if (i < S0 + S1 + 512) {
        int t = i - S0 - S1;
        int sel = t >> 7, c = t & 127;
        const float* b = (sel == 0) ? bk0 : (sel == 1) ? bv0 : (sel == 2) ? bq0 : bs0;
        b0[t] = b[c];
    } else if (i < S0 + S1 + 1024) {
        int t = i - S0 - S1 - 512;
        int sel = t >> 7, c = t & 127;
        const float* b = (sel == 0) ? bk1 : (sel == 1) ? bv1 : (sel == 2) ? bq1 : bs1;
        b1[t] = b[c];
    }
}

// ---------------------------------------------------------------- dual-sector MFMA GEMM (R7/R10 structure, best measured)
// A staged through LDS with coalesced loads; counted-wait 2-deep pipeline.
// blockIdx.x <  s0blocks -> sector 0: Bt rows [0,256)   -> outb (bf16), rows rl0/n0
// blockIdx.x >= s0blocks -> sector 1: Bt rows [256,512) -> outf (f32),  rows rl1/n1
// Block tile 128(M) x 256(N), BK=32. 512 threads = 8 waves (2m x 4n), wave tile 64x64.
// B: triple-buffered LDS via global_load_lds (prefetch dist 2). A: reg-staged (raw,
// cvt deferred to ds_write), double-buffered LDS. Raw s_barrier with lgkmcnt(0) only.
template <typename AT>
__global__ __launch_bounds__(512, 4) void gemm_dual_kernel(const AT* __restrict__ A,
                                                           const __bf16* __restrict__ Bt,
                                                           const float* __restrict__ bias,
                                                           __bf16* __restrict__ outb,
                                                           float* __restrict__ outf,
                                                           const int* __restrict__ rl0,
                                                           const int* __restrict__ np0, int ns0,
                                                           const int* __restrict__ rl1,
                                                           const int* __restrict__ np1, int ns1,
                                                           int K, int s0blocks) {
    __shared__ __align__(16) __bf16 Asl[2][128 * 32];   // 16 KB
    __shared__ __align__(16) __bf16 Bsl[3][256 * 32];   // 48 KB
    const int bx = blockIdx.x;
    const int sector = (bx >= s0blocks) ? 1 : 0;
    const int tile0  = sector ? bx - s0blocks : bx;
    const int tstr   = sector ? (gridDim.x - s0blocks) : s0blocks;
    const int* rowlist = sector ? rl1 : rl0;
    const int* nptr = sector ? np1 : np0;
    const int nrows = nptr ? *nptr : (sector ? ns1 : ns0);
    if (nrows <= 0) return;
    const __bf16* BT = Bt + (size_t)(sector ? 256 : 0) * K;
    const float* bs = bias + (sector ? 256 : 0);
    const int ntiles = (nrows + 127) >> 7;
    const int NT = K >> 5;                       // K-steps (32 for layer0, 4 for layer1)

    const int tid = threadIdx.x;
    const int lane = tid & 63, wid = tid >> 6;   // wid 0..7
    const int wm = wid >> 2, wn = wid & 3;       // 2 x 4 wave grid
    const int fr = lane & 15, quad = lane >> 4;
    const int rr = tid >> 2;                     // 0..127 staging row
    const int kc8 = (tid & 3) << 3;              // A global k-offset (coalesced, unswizzled)
    const int swch = (((tid & 3) ^ (rr & 3)) << 3);  // swizzled chunk offset (elements)
    const int qsw8 = ((quad ^ (fr & 3)) << 3);       // fragment-read chunk offset (elements)

    // B global source: pre-swizzled chunk so the linear gl_lds dest realizes the
    // swizzled layout (element (row,kc) lives at chunk kc ^ (row&3)).
    const __bf16* gB = BT + (size_t)rr * K + swch;

    for (int mt = tile0; mt < ntiles; mt += tstr) {
        const int mbase = mt << 7;
        int lr = mbase + rr;
        if (lr >= nrows) lr = nrows - 1;
        const int gr = rowlist ? rowlist[lr] : lr;
        const AT* gA = A + (size_t)gr * K + kc8;

        f32x4 acc[4][4];
#pragma unroll
        for (int i = 0; i < 4; i++)
#pragma unroll
            for (int j = 0; j < 4; j++) acc[i][j] = (f32x4){0.f, 0.f, 0.f, 0.f};

        __syncthreads();   // LDS reuse guard across mt iterations (full drain, once per tile)

        // ---- prologue: stage tiles 0 and 1
        ARaw<AT> a0, aC;
        {
            __bf16* bd0 = &Bsl[0][(size_t)(wid << 4) * 32];
            gl_lds16(gB, bd0);
            gl_lds16(gB + (size_t)128 * K, bd0 + 128 * 32);
            loadAraw(gA, a0);
            __bf16* bd1 = &Bsl[1][(size_t)(wid << 4) * 32];
            gl_lds16(gB + 32, bd1);
            gl_lds16(gB + (size_t)128 * K + 32, bd1 + 128 * 32);
            loadAraw(gA + 32, aC);
            // compiler inserts counted vmcnt here (a0 use; B1/A1 still in flight)
            *(bf16x8*)&Asl[0][rr * 32 + swch] = cvtA<AT>(a0);
            asm volatile("s_waitcnt lgkmcnt(0)" ::: "memory");
            __builtin_amdgcn_s_barrier();   // B0 already drained by the a0-wait above
        }

        // ---- pipelined K-loop
        for (int k = 0; k < NT; ++k) {
            const __bf16* As = Asl[k & 1];
            const __bf16* Bs = Bsl[k % 3];
            bf16x8 af[4];
#pragma unroll
            for (int mi = 0; mi < 4; mi++)
                af[mi] = *(const bf16x8*)&As[(wm * 64 + mi * 16 + fr) * 32 + qsw8];
#pragma unroll
            for (int ni = 0; ni < 4; ni++) {
                bf16x8 b8 = *(const bf16x8*)&Bs[(wn * 64 + ni * 16 + fr) * 32 + qsw8];
#pragma unroll
                for (int mi = 0; mi < 4; mi++)
                    acc[mi][ni] = __builtin_amdgcn_mfma_f32_16x16x32_bf16(af[mi], b8, acc[mi][ni], 0, 0, 0);
            }
            const bool wr = (k + 1 < NT);
            const bool pf = (k + 2 < NT);
            if (pf) {   // issue B(k+2) gl_lds first (no dest regs)
                const int kn = (k + 2) << 5;
                __bf16* bd = &Bsl[(k + 2) % 3][(size_t)(wid << 4) * 32];
                gl_lds16(gB + kn, bd);
                gl_lds16(gB + (size_t)128 * K + kn, bd + 128 * 32);
            }
            if (wr) {
                // consume aC = A(k+1): compiler waits vmcnt(2) (only the 2 new gl_lds pending)
                // -> also guarantees B(k+1) landed before the barrier below.
                *(bf16x8*)&Asl[(k + 1) & 1][rr * 32 + swch] = cvtA<AT>(aC);
            }
            if (pf) {   // reload aC with A(k+2) (regs dead after the write above)
                loadAraw(gA + ((k + 2) << 5), aC);
            }
            if (wr) {
                asm volatile("s_waitcnt lgkmcnt(0)" ::: "memory");
                __builtin_amdgcn_s_barrier();
            }
        }

        // ---- epilogue
#pragma unroll
        for (int mi = 0; mi < 4; mi++)
#pragma unroll
            for (int ni = 0; ni < 4; ni++) {
                int rl = wm * 64 + mi * 16 + quad * 4;
                int cl = wn * 64 + ni * 16 + fr;
                float b = bs[cl];
#pragma unroll
                for (int r = 0; r < 4; r++) {
                    int lr2 = mbase + rl + r;
                    if (lr2 < nrows) {
                        int gr2 = rowlist ? rowlist[lr2] : lr2;
                        float v = acc[mi][ni][r] + b;
                        if (sector == 0) outb[(size_t)gr2 * 256 + cl] = (__bf16)v;
                        else             outf[(size_t)gr2 * 256 + cl] = v;
                    }
                }
            }
    }
}

// ---------------------------------------------------------------- per-dst online-softmax attention (layer 0)
// q,s f32 from qs[node][0:128 / 128:256]; k,v bf16 from kvb[src][0:128 / 128:256].
// out = relu(agg+s) bf16 by node.
__global__ __launch_bounds__(256) void attn_kernel(const float* __restrict__ qs,
                                                   const __bf16* __restrict__ kvb,
                                                   const int* __restrict__ off,
                                                   const int* __restrict__ srcs,
                                                   const int* __restrict__ nodelist,
                                                   const int* __restrict__ nptr, int nstatic,
                                                   __bf16* __restrict__ outb) {
    int n = nptr ? *nptr : nstatic;
    int lane = threadIdx.x & 63;
    int w0 = blockIdx.x * 4 + (threadIdx.x >> 6);
    int nw = gridDim.x * 4;
    const float scale = 0.08838834764831845f;  // 1/sqrt(128)
    for (int w = w0; w < n; w += nw) {
        int node = nodelist ? nodelist[w] : w;
        const float* bq = qs + (size_t)node * 256;
        float2 q = *(const float2*)(bq + 2 * lane);
        float2 s = *(const float2*)(bq + 128 + 2 * lane);
        int e0 = off[node], e1 = off[node + 1];
        float m = -INFINITY, l = 0.f;
        float ax = 0.f, ay = 0.f;
        bf16x2 kc = {(__bf16)0.f, (__bf16)0.f}, vc = kc;
        if (e0 < e1) {
            const __bf16* p = kvb + (size_t)srcs[e0] * 256;
            kc = *(const bf16x2*)(p + 2 * lane);
            vc = *(const bf16x2*)(p + 128 + 2 * lane);
        }
        for (int e = e0; e < e1; ++e) {
            bf16x2 kn = {(__bf16)0.f, (__bf16)0.f}, vn = kn;
            if (e + 1 < e1) {  // prefetch next edge before the serial chain
                const __bf16* p = kvb + (size_t)srcs[e + 1] * 256;
                kn = *(const bf16x2*)(p + 2 * lane);
                vn = *(const bf16x2*)(p + 128 + 2 * lane);
            }
            float t = q.x * (float)kc.x + q.y * (float)kc.y;
#pragma unroll
            for (int o = 32; o > 0; o >>= 1) t += __shfl_xor(t, o, 64);
            float sc = t * scale;
            float mn = fmaxf(m, sc);
            float al = __expf(m - mn);
            float ee = __expf(sc - mn);
            ax = ax * al + ee * (float)vc.x;
            ay = ay * al + ee * (float)vc.y;
            l = l * al + ee;
            m = mn;
            kc = kn; vc = vn;
        }
        float inv = 1.f / (l + 1e-16f);
        float ox = ax * inv + s.x, oy = ay * inv + s.y;
        bf16x2 o2 = {(__bf16)fmaxf(ox, 0.f), (__bf16)fmaxf(oy, 0.f)};
        *(bf16x2*)(outb + (size_t)node * 128 + 2 * lane) = o2;
    }
}

// ---------------------------------------------------------------- fused layer-1 attention + MLP head
// One wave per graph b: online-softmax over idx[b]'s in-edges -> h = relu(agg+s)
// kept in a per-wave LDS strip, then 128->128->64->1 head inline.
__global__ __launch_bounds__(256) void attn_mlp_kernel(const float* __restrict__ qs,
                                                       const __bf16* __restrict__ kvb,
                                                       const int* __restrict__ off,
                                                       const int* __restrict__ srcs,
                                                       const int* __restrict__ idx,
                                                       const float* __restrict__ mw1, const float* __restrict__ mb1,
                                                       const float* __restrict__ mw2, const float* __restrict__ mb2,
                                                       const float* __restrict__ mw3, const float* __restrict__ mb3,
                                                       float* __restrict__ out, int B) {
    __shared__ float hl[4][128];
    __shared__ float z1l[4][128];
    int lane = threadIdx.x & 63;
    int ws = threadIdx.x >> 6;
    int w = blockIdx.x * 4 + ws;
    if (w >= B) return;
    int node = idx[w];
    const float scale = 0.08838834764831845f;  // 1/sqrt(128)
    const float* bq = qs + (size_t)node * 256;
    float2 q = *(const float2*)(bq + 2 * lane);
    float2 s = *(const float2*)(bq + 128 + 2 * lane);
    int e0 = off[node], e1 = off[node + 1];
    float m = -INFINITY, l = 0.f;
    float ax = 0.f, ay = 0.f;
    bf16x2 kc = {(__bf16)0.f, (__bf16)0.f}, vc = kc;
    if (e0 < e1) {
        const __bf16* p = kvb + (size_t)srcs[e0] * 256;
        kc = *(const bf16x2*)(p + 2 * lane);
        vc = *(const bf16x2*)(p + 128 + 2 * lane);
    }
    for (int e = e0; e < e1; ++e) {
        bf16x2 kn = {(__bf16)0.f, (__bf16)0.f}, vn = kn;
        if (e + 1 < e1) {
            const __bf16* p = kvb + (size_t)srcs[e + 1] * 256;
            kn = *(const bf16x2*)(p + 2 * lane);
            vn = *(const bf16x2*)(p + 128 + 2 * lane);
        }
        float t = q.x * (float)kc.x + q.y * (float)kc.y;
#pragma unroll
        for (int o = 32; o > 0; o >>= 1) t += __shfl_xor(t, o, 64);
        float sc = t * scale;
        float mn = fmaxf(m, sc);
        float al = __expf(m - mn);
        float ee = __expf(sc - mn);
        ax = ax * al + ee * (float)vc.x;
        ay = ay * al + ee * (float)vc.y;
        l = l * al + ee;
        m = mn;
        kc = kn; vc = vn;
    }
    float inv = 1.f / (l + 1e-16f);
    hl[ws][2 * lane]     = fmaxf(ax * inv + s.x, 0.f);
    hl[ws][2 * lane + 1] = fmaxf(ay * inv + s.y, 0.f);
    // wave-local LDS exchange: drain ds writes before cross-lane reads (no block barrier needed)
    asm volatile("s_waitcnt lgkmcnt(0)" ::: "memory");
    // z1[t] for t = 2*lane, 2*lane+1
    float a0 = mb1[2 * lane], a1 = mb1[2 * lane + 1];
#pragma unroll 8
    for (int k = 0; k < 128; ++k) {
        float hk = hl[ws][k];
        float2 wv = *(const float2*)&mw1[(size_t)k * 128 + 2 * lane];
        a0 += hk * wv.x;
        a1 += hk * wv.y;
    }
    z1l[ws][2 * lane]     = fmaxf(a0, 0.f);
    z1l[ws][2 * lane + 1] = fmaxf(a1, 0.f);
    asm volatile("s_waitcnt lgkmcnt(0)" ::: "memory");
    // z2[lane] (64 outputs == 64 lanes)
    float a2 = mb2[lane];
#pragma unroll 8
    for (int k = 0; k < 128; ++k) a2 += z1l[ws][k] * mw2[(size_t)k * 64 + lane];
    float z2 = fmaxf(a2, 0.f);
    float p = z2 * mw3[lane];
#pragma unroll
    for (int o = 32; o > 0; o >>= 1) p += __shfl_xor(p, o, 64);
    if (lane == 0) out[w] = 1.f / (1.f + __expf(-(p + mb3[0])));
}

// ---------------------------------------------------------------- launch
extern "C" void kernel_launch(void* const* d_in, const int* in_sizes, int n_in,
                              void* d_out, int out_size, void* d_ws, size_t ws_size,
                              hipStream_t stream) {
    const float* x   = (const float*)d_in[0];
    const int*   ei  = (const int*)d_in[1];
    const int*   idx = (const int*)d_in[2];
    const float* wq0 = (const float*)d_in[3];
    const float* wk0 = (const float*)d_in[4];
    const float* wv0 = (const float*)d_in[5];
    const float* ws0 = (const float*)d_in[6];
    const float* bq0 = (const float*)d_in[7];
    const float* bk0 = (const float*)d_in[8];
    const float* bv0 = (const float*)d_in[9];
    const float* bs0 = (const float*)d_in[10];
    const float* wq1 = (const float*)d_in[11];
    const float* wk1 = (const float*)d_in[12];
    const float* wv1 = (const float*)d_in[13];
    const float* ws1 = (const float*)d_in[14];
    const float* bq1 = (const float*)d_in[15];
    const float* bk1 = (const float*)d_in[16];
    const float* bv1 = (const float*)d_in[17];
    const float* bs1 = (const float*)d_in[18];
    const float* mw1 = (const float*)d_in[19];
    const float* mb1 = (const float*)d_in[20];
    const float* mw2 = (const float*)d_in[21];
    const float* mb2 = (const float*)d_in[22];
    const float* mw3 = (const float*)d_in[23];
    const float* mb3 = (const float*)d_in[24];
    float* out = (float*)d_out;

    const int Nn = in_sizes[0] / 1024;  // 50000
    const int E  = in_sizes[1] / 2;     // 600000
    const int B  = in_sizes[2];         // 1000
    const int* esrc = ei;
    const int* edst = ei + E;
    const int degPad = ((Nn + 8191) >> 13) << 13;

    uintptr_t base = (uintptr_t)d_ws;
    auto alloc = [&](size_t bytes) -> void* {
        uintptr_t p = (base + 255) & ~(uintptr_t)255;
        base = p + bytes;
        return (void*)p;
    };
    __bf16* kvb  = (__bf16*)alloc((size_t)Nn * 256 * 2);   // 25.6 MB; kv1b aliases (kv0 dead after attn0)
    __bf16* kv1b = kvb;
    float*  qs   = (float*)alloc((size_t)Nn * 256 * 4);    // 51.2 MB; qs1 aliases
    float*  qs1  = qs;
    __bf16* h0b  = (__bf16*)alloc((size_t)Nn * 128 * 2);   // 12.8 MB (only U rows valid)
    __bf16* w0t  = (__bf16*)alloc(512 * 1024 * 2);
    __bf16* w1t  = (__bf16*)alloc(512 * 128 * 2);
    float*  b0   = (float*)alloc(512 * 4);
    float*  b1   = (float*)alloc(512 * 4);
    // zero region (one memset): deg(padded), cursor, flagIdx(byte), flagU(byte), nU
    int* deg               = (int*)alloc((size_t)degPad * 4);
    int* cursor            = (int*)alloc((size_t)Nn * 4);
    unsigned char* flagIdx = (unsigned char*)alloc((size_t)Nn);
    unsigned char* flagU   = (unsigned char*)alloc((size_t)Nn);
    int* nU                = (int*)alloc(256);
    size_t zbytes = (uintptr_t)nU + 256 - (uintptr_t)deg;
    int* off     = (int*)alloc((size_t)(Nn + 1) * 4);
    int* srcs    = (int*)alloc((size_t)E * 4);
    int* U       = (int*)alloc((size_t)Nn * 4);

    hipMemsetAsync(deg, 0, zbytes, stream);

    // ---- U set + CSR (atomic diet: only ~26% of edges have dst in U -> gate all atomics)
    mark_idx_kernel<<<(B + 255) / 256, 256, 0, stream>>>(idx, flagIdx, flagU, B);
    mark_src_kernel<<<(E + 255) / 256, 256, 0, stream>>>(esrc, edst, flagIdx, flagU, E);
    deg_kernel<<<(E + 255) / 256, 256, 0, stream>>>(edst, flagU, deg, E);
    scan8_kernel<<<1, 1024, 0, stream>>>(deg, off, Nn, flagU, U, nU);
    scatter_kernel<<<(E + 255) / 256, 256, 0, stream>>>(esrc, edst, flagU, off, cursor, srcs, E);

    // ---- weights
    pack_w_kernel<<<(512 * 1024 + 512 * 128 + 1024 + 255) / 256, 256, 0, stream>>>(
        wq0, wk0, wv0, ws0, wq1, wk1, wv1, ws1,
        bq0, bk0, bv0, bs0, bq1, bk1, bv1, bs1, w0t, w1t, b0, b1);

    const int mtiles = (Nn + 127) / 128;  // 391

    // ---- layer 0: sector0 = k|v all rows -> kvb(bf16); sector1 = q|s U rows -> qs(f32)
    // grid: 391 sector0 blocks (1 tile each) + 121 sector1 blocks (grid-stride) = 512, all live
    gemm_dual_kernel<float><<<mtiles + 121, 512, 0, stream>>>(x, w0t, b0, kvb, qs,
                                                              nullptr, nullptr, Nn,
                                                              U, nU, 0, 1024, mtiles);
    attn_kernel<<<4096, 256, 0, stream>>>(qs, kvb, off, srcs, U, nU, 0, h0b);

    // ---- layer 1: sector0 = k|v U rows -> kv1b(bf16); sector1 = q|s idx rows -> qs1(f32)
    gemm_dual_kernel<__bf16><<<144, 512, 0, stream>>>(h0b, w1t, b1, kv1b, qs1,
                                                      U, nU, 0,
                                                      idx, nullptr, B, 128, 128);
    // ---- fused layer-1 attention + MLP head
    attn_mlp_kernel<<<(B + 3) / 4, 256, 0, stream>>>(qs1, kv1b, off, srcs, idx,
                                                     mw1, mb1, mw2, mb2, mw3, mb3, out, B);
}